// Round 3
// baseline (128.967 us; speedup 1.0000x reference)
//
#include <hip/hip_runtime.h>

#define SS 4096
#define DD 64
#define NH 16
#define QB 128
#define NQB (SS / QB)      // 32
#define KVT 64
#define NKV (SS / KVT)     // 64
#define TILE_BYTES 8192    // 64 x 64 bf16

typedef float  fx4    __attribute__((ext_vector_type(4)));
typedef __bf16 bf16x8 __attribute__((ext_vector_type(8)));
typedef short  sx4    __attribute__((ext_vector_type(4)));

typedef __attribute__((address_space(1))) const unsigned int GU32;
typedef __attribute__((address_space(3))) unsigned int       LU32;

__device__ __forceinline__ void gload16(const void* g, void* l) {
    __builtin_amdgcn_global_load_lds((GU32*)g, (LU32*)l, 16, 0, 0);
}

__device__ __forceinline__ float fast_exp2(float x) {
    return __builtin_amdgcn_exp2f(x);   // v_exp_f32: 2^x
}

// ---------------- pre-pass: f32 K/V -> bf16 swizzled tile images ----------------
// K image: per (h,t) an 8 KB tile; row r (=k in tile) is 128 B; the 16-byte
// d-chunk c (d = 8c..8c+7) is stored at chunk slot (c ^ (r&7)).
// V image: same but rows are d (V transposed), chunks are k-chunks.
__global__ __launch_bounds__(256)
void prep_kernel(const float* __restrict__ Kg, const float* __restrict__ Vg,
                 char* __restrict__ Kimg, char* __restrict__ Vimg)
{
    __shared__ __bf16 lv[64][72];
    const int tid = threadIdx.x;
    const int h = (int)blockIdx.x >> 6;
    const int t = (int)blockIdx.x & 63;
    const int r = tid >> 2;                       // 0..63
    const size_t rowbase = ((size_t)h * SS + (size_t)t * KVT) * DD;

    // ---- K ----
    {
        char* kdst = Kimg + (size_t)(h * NKV + t) * TILE_BYTES;
        const float* src = Kg + rowbase + (size_t)r * DD;
#pragma unroll
        for (int cc = 0; cc < 2; ++cc) {
            const int c = (tid & 3) * 2 + cc;     // 0..7
            fx4 f0 = *(const fx4*)(src + c * 8);
            fx4 f1 = *(const fx4*)(src + c * 8 + 4);
            bf16x8 b;
#pragma unroll
            for (int j = 0; j < 4; ++j) { b[j] = (__bf16)f0[j]; b[4 + j] = (__bf16)f1[j]; }
            *(bf16x8*)(kdst + r * 128 + ((c ^ (r & 7)) << 4)) = b;
        }
    }

    // ---- V: load tile to LDS (row-major), then write transposed ----
    {
        const float* src = Vg + rowbase + (size_t)r * DD + (tid & 3) * 16;
#pragma unroll
        for (int qq = 0; qq < 4; ++qq) {
            fx4 f = *(const fx4*)(src + qq * 4);
#pragma unroll
            for (int j = 0; j < 4; ++j) lv[r][(tid & 3) * 16 + qq * 4 + j] = (__bf16)f[j];
        }
    }
    __syncthreads();
    {
        char* vdst = Vimg + (size_t)(h * NKV + t) * TILE_BYTES;
        const int d = r;                          // VT row
#pragma unroll
        for (int cc = 0; cc < 2; ++cc) {
            const int c = (tid & 3) * 2 + cc;     // k-chunk 0..7
            bf16x8 b;
#pragma unroll
            for (int j = 0; j < 8; ++j) b[j] = lv[c * 8 + j][d];
            *(bf16x8*)(vdst + d * 128 + ((c ^ (d & 7)) << 4)) = b;
        }
    }
}

// ---------------- main flash-attention kernel ----------------
__global__ __launch_bounds__(256, 2)
void attn_fwd(const float* __restrict__ Qg, const char* __restrict__ Kimg,
              const char* __restrict__ Vimg, float* __restrict__ Og)
{
    __shared__ __align__(16) char lK[2][TILE_BYTES];
    __shared__ __align__(16) char lV[2][TILE_BYTES];

    const int tid  = threadIdx.x;
    const int wid  = tid >> 6;
    const int lane = tid & 63;
    const int lr   = lane & 15;
    const int g    = lane >> 4;

    // block pairing: (2i, 2i+1) -> (heavy, light) q-blocks, pair sum constant
    const int p      = (int)blockIdx.x >> 1;
    const int parity = (int)blockIdx.x & 1;
    const int h      = p & 15;
    const int slot   = p >> 4;                    // 0..15
    const int qb     = parity ? slot : (31 - slot);

    const int ntiles = 2 * qb + 2;
    const int q0     = qb * QB + wid * 32;        // wave owns 32 q rows (2 subtiles)

    const float* Qh = Qg + (size_t)h * SS * DD;
    float*       Oh = Og + (size_t)h * SS * DD;
    const char*  Kh = Kimg + (size_t)(h * NKV) * TILE_BYTES;
    const char*  Vh = Vimg + (size_t)(h * NKV) * TILE_BYTES;

    // fold 1/sqrt(64) and log2(e): softmax via exp2
    const float QSCALE = 0.125f * 1.44269504088896f;

    // Q fragments (held all kernel)
    bf16x8 qa[2][2];
#pragma unroll
    for (int u = 0; u < 2; ++u) {
        const int qrow = q0 + 16 * u + lr;
#pragma unroll
        for (int h2 = 0; h2 < 2; ++h2) {
            const float* src = Qh + (size_t)qrow * DD + h2 * 32 + g * 8;
            fx4 f0 = *(const fx4*)(src);
            fx4 f1 = *(const fx4*)(src + 4);
            bf16x8 tq;
#pragma unroll
            for (int j = 0; j < 4; ++j) {
                tq[j]     = (__bf16)(f0[j] * QSCALE);
                tq[j + 4] = (__bf16)(f1[j] * QSCALE);
            }
            qa[u][h2] = tq;
        }
    }

    fx4 acc[2][4];
#pragma unroll
    for (int u = 0; u < 2; ++u)
#pragma unroll
        for (int d0 = 0; d0 < 4; ++d0) acc[u][d0] = (fx4){0.f, 0.f, 0.f, 0.f};
    float m_run[2] = {-1e30f, -1e30f};
    float l_run[2] = {0.f, 0.f};

#define STAGE(buf, tt)                                                          \
    do {                                                                        \
        const char* kt_ = Kh + (size_t)(tt) * TILE_BYTES;                       \
        const char* vt_ = Vh + (size_t)(tt) * TILE_BYTES;                       \
        const int so_ = wid * 2048 + lane * 16;                                 \
        gload16(kt_ + so_,        &lK[buf][wid * 2048]);                        \
        gload16(kt_ + so_ + 1024, &lK[buf][wid * 2048 + 1024]);                 \
        gload16(vt_ + so_,        &lV[buf][wid * 2048]);                        \
        gload16(vt_ + so_ + 1024, &lV[buf][wid * 2048 + 1024]);                 \
    } while (0)

    STAGE(0, 0);
    __syncthreads();

    int cur = 0;
    for (int t = 0; t < ntiles; ++t) {
        if (t + 1 < ntiles) STAGE(cur ^ 1, t + 1);   // prefetch next tile

        // ---- QK^T (swapped: A=K tile rows, B=Q) ----
        float s[2][4][4];
        __builtin_amdgcn_s_setprio(1);
#pragma unroll
        for (int ks = 0; ks < 4; ++ks) {
            const int row = ks * 16 + lr;
            const char* base = &lK[cur][row * 128];
            const bf16x8 ka0 = *(const bf16x8*)(base + (((g    ) ^ (row & 7)) << 4));
            const bf16x8 ka1 = *(const bf16x8*)(base + (((g ^ 4) ^ (row & 7)) << 4));
#pragma unroll
            for (int u = 0; u < 2; ++u) {
                fx4 st = (fx4){0.f, 0.f, 0.f, 0.f};
                st = __builtin_amdgcn_mfma_f32_16x16x32_bf16(ka0, qa[u][0], st, 0, 0, 0);
                st = __builtin_amdgcn_mfma_f32_16x16x32_bf16(ka1, qa[u][1], st, 0, 0, 0);
#pragma unroll
                for (int r = 0; r < 4; ++r) s[u][ks][r] = st[r];
            }
        }
        __builtin_amdgcn_s_setprio(0);

        // ---- causal mask: only the last two tiles can touch the diagonal ----
        if (t >= ntiles - 2) {
            const int kv0 = t * KVT;
#pragma unroll
            for (int u = 0; u < 2; ++u) {
                const int qrow = q0 + 16 * u + lr;
#pragma unroll
                for (int ks = 0; ks < 4; ++ks)
#pragma unroll
                    for (int r = 0; r < 4; ++r) {
                        const int kk = kv0 + ks * 16 + 4 * g + r;
                        if (kk > qrow) s[u][ks][r] = -1e30f;
                    }
            }
        }

        // ---- online softmax per q-subtile ----
        sx4 pa[2][4];
#pragma unroll
        for (int u = 0; u < 2; ++u) {
            float tmax = -1e30f;
#pragma unroll
            for (int ks = 0; ks < 4; ++ks)
#pragma unroll
                for (int r = 0; r < 4; ++r) tmax = fmaxf(tmax, s[u][ks][r]);
            tmax = fmaxf(tmax, __shfl_xor(tmax, 16));
            tmax = fmaxf(tmax, __shfl_xor(tmax, 32));
            const float m_new = fmaxf(m_run[u], tmax);
            const float alpha = fast_exp2(m_run[u] - m_new);
            m_run[u] = m_new;

            float psum = 0.f;
            float pv[4][4];
#pragma unroll
            for (int ks = 0; ks < 4; ++ks)
#pragma unroll
                for (int r = 0; r < 4; ++r) {
                    pv[ks][r] = fast_exp2(s[u][ks][r] - m_new);
                    psum += pv[ks][r];
                }
            psum += __shfl_xor(psum, 16);
            psum += __shfl_xor(psum, 32);
            l_run[u] = l_run[u] * alpha + psum;

#pragma unroll
            for (int ks = 0; ks < 4; ++ks) {
                sx4 t4;
#pragma unroll
                for (int j = 0; j < 4; ++j) {
                    const __bf16 pb = (__bf16)pv[ks][j];
                    t4[j] = __builtin_bit_cast(short, pb);
                }
                pa[u][ks] = t4;
            }

            float av[4];
#pragma unroll
            for (int r = 0; r < 4; ++r) av[r] = __shfl(alpha, 4 * g + r);
#pragma unroll
            for (int d0 = 0; d0 < 4; ++d0) {
                fx4 a = acc[u][d0];
                a[0] *= av[0]; a[1] *= av[1]; a[2] *= av[2]; a[3] *= av[3];
                acc[u][d0] = a;
            }
        }

        // ---- PV: P fragments are already MFMA A-layout; V^T read swizzled ----
        __builtin_amdgcn_s_setprio(1);
#pragma unroll
        for (int ks = 0; ks < 4; ++ks) {
            const int s0 = ks * 2 + (g >> 1);     // k-chunk slot
#pragma unroll
            for (int d0 = 0; d0 < 4; ++d0) {
                const int row = d0 * 16 + lr;
                const sx4 vb = *(const sx4*)(&lV[cur][row * 128 +
                                ((s0 ^ (row & 7)) << 4) + (g & 1) * 8]);
                acc[0][d0] = __builtin_amdgcn_mfma_f32_16x16x16bf16_1k(pa[0][ks], vb, acc[0][d0], 0, 0, 0);
                acc[1][d0] = __builtin_amdgcn_mfma_f32_16x16x16bf16_1k(pa[1][ks], vb, acc[1][d0], 0, 0, 0);
            }
        }
        __builtin_amdgcn_s_setprio(0);

        if (t + 1 < ntiles) __syncthreads();      // next tile staged + all reads done
        cur ^= 1;
    }

    // ---- epilogue ----
#pragma unroll
    for (int u = 0; u < 2; ++u) {
        const float linv = 1.f / l_run[u];
        float bv[4];
#pragma unroll
        for (int r = 0; r < 4; ++r) bv[r] = __shfl(linv, 4 * g + r);
#pragma unroll
        for (int d0 = 0; d0 < 4; ++d0)
#pragma unroll
            for (int r = 0; r < 4; ++r)
                Oh[(size_t)(q0 + 16 * u + 4 * g + r) * DD + d0 * 16 + lr] = acc[u][d0][r] * bv[r];
    }
}

extern "C" void kernel_launch(void* const* d_in, const int* in_sizes, int n_in,
                              void* d_out, int out_size, void* d_ws, size_t ws_size,
                              hipStream_t stream)
{
    (void)in_sizes; (void)n_in; (void)out_size; (void)ws_size;
    const float* q = (const float*)d_in[0];
    const float* k = (const float*)d_in[1];
    const float* v = (const float*)d_in[2];
    float*       o = (float*)d_out;

    char* ws   = (char*)d_ws;
    char* Kimg = ws;                       // 8 MB
    char* Vimg = ws + ((size_t)1 << 23);   // 8 MB

    hipLaunchKernelGGL(prep_kernel, dim3(NH * NKV), dim3(256), 0, stream, k, v, Kimg, Vimg);
    hipLaunchKernelGGL(attn_fwd,    dim3(NH * NQB), dim3(256), 0, stream, q, Kimg, Vimg, o);
}

// Round 4
// 112.632 us; speedup vs baseline: 1.1450x; 1.1450x over previous
//
#include <hip/hip_runtime.h>

#define SS 4096
#define DD 64
#define NH 16
#define QB 128
#define NQB (SS / QB)      // 32
#define KVT 64
#define NKV (SS / KVT)     // 64
#define TILE_BYTES 8192    // 64 x 64 bf16

typedef float  fx4    __attribute__((ext_vector_type(4)));
typedef __bf16 bf16x8 __attribute__((ext_vector_type(8)));
typedef short  sx4    __attribute__((ext_vector_type(4)));

typedef __attribute__((address_space(1))) const unsigned int GU32;
typedef __attribute__((address_space(3))) unsigned int       LU32;

__device__ __forceinline__ void gload16(const void* g, void* l) {
    __builtin_amdgcn_global_load_lds((GU32*)g, (LU32*)l, 16, 0, 0);
}

__device__ __forceinline__ float fast_exp2(float x) {
    return __builtin_amdgcn_exp2f(x);   // v_exp_f32: 2^x
}

// ---------------- pre-pass: f32 K/V -> bf16 swizzled tile images ----------------
__global__ __launch_bounds__(256)
void prep_kernel(const float* __restrict__ Kg, const float* __restrict__ Vg,
                 char* __restrict__ Kimg, char* __restrict__ Vimg)
{
    __shared__ __bf16 lv[64][72];
    const int tid = threadIdx.x;
    const int h = (int)blockIdx.x >> 6;
    const int t = (int)blockIdx.x & 63;
    const int r = tid >> 2;                       // 0..63
    const size_t rowbase = ((size_t)h * SS + (size_t)t * KVT) * DD;

    // ---- K ----
    {
        char* kdst = Kimg + (size_t)(h * NKV + t) * TILE_BYTES;
        const float* src = Kg + rowbase + (size_t)r * DD;
#pragma unroll
        for (int cc = 0; cc < 2; ++cc) {
            const int c = (tid & 3) * 2 + cc;     // 0..7
            fx4 f0 = *(const fx4*)(src + c * 8);
            fx4 f1 = *(const fx4*)(src + c * 8 + 4);
            bf16x8 b;
#pragma unroll
            for (int j = 0; j < 4; ++j) { b[j] = (__bf16)f0[j]; b[4 + j] = (__bf16)f1[j]; }
            *(bf16x8*)(kdst + r * 128 + ((c ^ (r & 7)) << 4)) = b;
        }
    }

    // ---- V: load tile to LDS (row-major), then write transposed ----
    {
        const float* src = Vg + rowbase + (size_t)r * DD + (tid & 3) * 16;
#pragma unroll
        for (int qq = 0; qq < 4; ++qq) {
            fx4 f = *(const fx4*)(src + qq * 4);
#pragma unroll
            for (int j = 0; j < 4; ++j) lv[r][(tid & 3) * 16 + qq * 4 + j] = (__bf16)f[j];
        }
    }
    __syncthreads();
    {
        char* vdst = Vimg + (size_t)(h * NKV + t) * TILE_BYTES;
        const int d = r;                          // VT row
#pragma unroll
        for (int cc = 0; cc < 2; ++cc) {
            const int c = (tid & 3) * 2 + cc;     // k-chunk 0..7
            bf16x8 b;
#pragma unroll
            for (int j = 0; j < 8; ++j) b[j] = lv[c * 8 + j][d];
            *(bf16x8*)(vdst + d * 128 + ((c ^ (d & 7)) << 4)) = b;
        }
    }
}

// ---------------- main flash-attention kernel ----------------
__global__ __launch_bounds__(256, 2)
void attn_fwd(const float* __restrict__ Qg, const char* __restrict__ Kimg,
              const char* __restrict__ Vimg, float* __restrict__ Og)
{
    __shared__ __align__(16) char lK[2][TILE_BYTES];
    __shared__ __align__(16) char lV[2][TILE_BYTES];

    const int tid  = threadIdx.x;
    const int wid  = tid >> 6;
    const int lane = tid & 63;
    const int lr   = lane & 15;
    const int g    = lane >> 4;

    // XCD-aware pairing: blocks b and b+256 co-locate on a CU under
    // round-robin XCD assignment; qb(b) + qb(b+256) = 31 -> constant 66
    // tiles per CU. Heavy half (qb 31..16) dispatches first.
    const int b  = (int)blockIdx.x;
    const int h  = b & 15;
    const int sl = (b >> 4) & 15;                 // 0..15
    const int qb = (b >> 8) ? sl : (31 - sl);

    const int ntiles = 2 * qb + 2;
    const int q0     = qb * QB + wid * 32;        // wave owns 32 q rows (2 subtiles)

    const float* Qh = Qg + (size_t)h * SS * DD;
    float*       Oh = Og + (size_t)h * SS * DD;
    const char*  Kh = Kimg + (size_t)(h * NKV) * TILE_BYTES;
    const char*  Vh = Vimg + (size_t)(h * NKV) * TILE_BYTES;

    // fold 1/sqrt(64) and log2(e): softmax via exp2 (THR below is in log2 units)
    const float QSCALE = 0.125f * 1.44269504088896f;

    // Q fragments (held all kernel)
    bf16x8 qa[2][2];
#pragma unroll
    for (int u = 0; u < 2; ++u) {
        const int qrow = q0 + 16 * u + lr;
#pragma unroll
        for (int h2 = 0; h2 < 2; ++h2) {
            const float* src = Qh + (size_t)qrow * DD + h2 * 32 + g * 8;
            fx4 f0 = *(const fx4*)(src);
            fx4 f1 = *(const fx4*)(src + 4);
            bf16x8 tq;
#pragma unroll
            for (int j = 0; j < 4; ++j) {
                tq[j]     = (__bf16)(f0[j] * QSCALE);
                tq[j + 4] = (__bf16)(f1[j] * QSCALE);
            }
            qa[u][h2] = tq;
        }
    }

    fx4 acc[2][4];
#pragma unroll
    for (int u = 0; u < 2; ++u)
#pragma unroll
        for (int d0 = 0; d0 < 4; ++d0) acc[u][d0] = (fx4){0.f, 0.f, 0.f, 0.f};
    float m_run = -1e30f;          // wave-level shared max (log2 units)
    float l_run[2] = {0.f, 0.f};   // lane-local partial row sums

#define STAGE(buf, tt)                                                          \
    do {                                                                        \
        const char* kt_ = Kh + (size_t)(tt) * TILE_BYTES;                       \
        const char* vt_ = Vh + (size_t)(tt) * TILE_BYTES;                       \
        const int so_ = wid * 2048 + lane * 16;                                 \
        gload16(kt_ + so_,        &lK[buf][wid * 2048]);                        \
        gload16(kt_ + so_ + 1024, &lK[buf][wid * 2048 + 1024]);                 \
        gload16(vt_ + so_,        &lV[buf][wid * 2048]);                        \
        gload16(vt_ + so_ + 1024, &lV[buf][wid * 2048 + 1024]);                 \
    } while (0)

    STAGE(0, 0);
    __syncthreads();

    int cur = 0;
    for (int t = 0; t < ntiles; ++t) {
        if (t + 1 < ntiles) STAGE(cur ^ 1, t + 1);   // prefetch next tile

        // ---- QK^T (swapped: A=K tile rows, B=Q) ----
        float s[2][4][4];
        __builtin_amdgcn_s_setprio(1);
#pragma unroll
        for (int ks = 0; ks < 4; ++ks) {
            const int row = ks * 16 + lr;
            const char* base = &lK[cur][row * 128];
            const bf16x8 ka0 = *(const bf16x8*)(base + (((g    ) ^ (row & 7)) << 4));
            const bf16x8 ka1 = *(const bf16x8*)(base + (((g ^ 4) ^ (row & 7)) << 4));
#pragma unroll
            for (int u = 0; u < 2; ++u) {
                fx4 st = (fx4){0.f, 0.f, 0.f, 0.f};
                st = __builtin_amdgcn_mfma_f32_16x16x32_bf16(ka0, qa[u][0], st, 0, 0, 0);
                st = __builtin_amdgcn_mfma_f32_16x16x32_bf16(ka1, qa[u][1], st, 0, 0, 0);
#pragma unroll
                for (int r = 0; r < 4; ++r) s[u][ks][r] = st[r];
            }
        }
        __builtin_amdgcn_s_setprio(0);

        // ---- causal mask: only the last two tiles can touch the diagonal ----
        if (t >= ntiles - 2) {
            const int kv0 = t * KVT;
#pragma unroll
            for (int u = 0; u < 2; ++u) {
                const int qrow = q0 + 16 * u + lr;
#pragma unroll
                for (int ks = 0; ks < 4; ++ks)
#pragma unroll
                    for (int r = 0; r < 4; ++r) {
                        const int kk = kv0 + ks * 16 + 4 * g + r;
                        if (kk > qrow) s[u][ks][r] = -1e30f;
                    }
            }
        }

        // ---- wave-level online softmax, defer-max (THR=8 log2 -> P<=256) ----
        float mloc[8];
#pragma unroll
        for (int i = 0; i < 8; ++i) {
            const int u = i >> 2, ks = i & 3;
            mloc[i] = fmaxf(fmaxf(s[u][ks][0], s[u][ks][1]),
                            fmaxf(s[u][ks][2], s[u][ks][3]));
        }
        float tmax = fmaxf(fmaxf(fmaxf(mloc[0], mloc[1]), fmaxf(mloc[2], mloc[3])),
                           fmaxf(fmaxf(mloc[4], mloc[5]), fmaxf(mloc[6], mloc[7])));
        tmax = fmaxf(tmax, __shfl_xor(tmax, 16));
        tmax = fmaxf(tmax, __shfl_xor(tmax, 32));   // wave-uniform now

        if (tmax > m_run + 8.0f) {                  // uniform branch; rare after t=0
            const float alpha = fast_exp2(m_run - tmax);
            m_run = tmax;
            l_run[0] *= alpha; l_run[1] *= alpha;
#pragma unroll
            for (int u = 0; u < 2; ++u)
#pragma unroll
                for (int d0 = 0; d0 < 4; ++d0) {
                    fx4 a = acc[u][d0];
                    a[0] *= alpha; a[1] *= alpha; a[2] *= alpha; a[3] *= alpha;
                    acc[u][d0] = a;
                }
        }

        sx4 pa[2][4];
#pragma unroll
        for (int u = 0; u < 2; ++u) {
            float e[4][4];
#pragma unroll
            for (int ks = 0; ks < 4; ++ks)
#pragma unroll
                for (int r = 0; r < 4; ++r)
                    e[ks][r] = fast_exp2(s[u][ks][r] - m_run);
            // balanced-tree partial sum; cross-lane reduce deferred to epilogue
            const float t0 = (e[0][0] + e[0][1]) + (e[0][2] + e[0][3]);
            const float t1 = (e[1][0] + e[1][1]) + (e[1][2] + e[1][3]);
            const float t2 = (e[2][0] + e[2][1]) + (e[2][2] + e[2][3]);
            const float t3 = (e[3][0] + e[3][1]) + (e[3][2] + e[3][3]);
            l_run[u] += (t0 + t1) + (t2 + t3);
#pragma unroll
            for (int ks = 0; ks < 4; ++ks) {
                sx4 t4;
#pragma unroll
                for (int j = 0; j < 4; ++j) {
                    const __bf16 pb = (__bf16)e[ks][j];
                    t4[j] = __builtin_bit_cast(short, pb);
                }
                pa[u][ks] = t4;
            }
        }

        // ---- PV: P fragments are already MFMA A-layout; V^T read swizzled ----
        __builtin_amdgcn_s_setprio(1);
#pragma unroll
        for (int ks = 0; ks < 4; ++ks) {
            const int s0 = ks * 2 + (g >> 1);     // k-chunk slot
#pragma unroll
            for (int d0 = 0; d0 < 4; ++d0) {
                const int row = d0 * 16 + lr;
                const sx4 vb = *(const sx4*)(&lV[cur][row * 128 +
                                ((s0 ^ (row & 7)) << 4) + (g & 1) * 8]);
                acc[0][d0] = __builtin_amdgcn_mfma_f32_16x16x16bf16_1k(pa[0][ks], vb, acc[0][d0], 0, 0, 0);
                acc[1][d0] = __builtin_amdgcn_mfma_f32_16x16x16bf16_1k(pa[1][ks], vb, acc[1][d0], 0, 0, 0);
            }
        }
        __builtin_amdgcn_s_setprio(0);

        if (t + 1 < ntiles) __syncthreads();      // next tile staged + all reads done
        cur ^= 1;
    }

    // ---- epilogue: one cross-lane l reduce, normalize, store ----
#pragma unroll
    for (int u = 0; u < 2; ++u) {
        float ls = l_run[u];
        ls += __shfl_xor(ls, 16);
        ls += __shfl_xor(ls, 32);
        const float linv = 1.f / ls;
        float bv[4];
#pragma unroll
        for (int r = 0; r < 4; ++r) bv[r] = __shfl(linv, 4 * g + r);
#pragma unroll
        for (int d0 = 0; d0 < 4; ++d0)
#pragma unroll
            for (int r = 0; r < 4; ++r)
                Oh[(size_t)(q0 + 16 * u + 4 * g + r) * DD + d0 * 16 + lr] = acc[u][d0][r] * bv[r];
    }
}

extern "C" void kernel_launch(void* const* d_in, const int* in_sizes, int n_in,
                              void* d_out, int out_size, void* d_ws, size_t ws_size,
                              hipStream_t stream)
{
    (void)in_sizes; (void)n_in; (void)out_size; (void)ws_size;
    const float* q = (const float*)d_in[0];
    const float* k = (const float*)d_in[1];
    const float* v = (const float*)d_in[2];
    float*       o = (float*)d_out;

    char* ws   = (char*)d_ws;
    char* Kimg = ws;                       // 8 MB
    char* Vimg = ws + ((size_t)1 << 23);   // 8 MB

    hipLaunchKernelGGL(prep_kernel, dim3(NH * NKV), dim3(256), 0, stream, k, v, Kimg, Vimg);
    hipLaunchKernelGGL(attn_fwd,    dim3(NH * NQB), dim3(256), 0, stream, q, Kimg, Vimg, o);
}

// Round 5
// 91.079 us; speedup vs baseline: 1.4160x; 1.2366x over previous
//
#include <hip/hip_runtime.h>

#define SS 4096
#define DD 64
#define NH 16
#define QB 128
#define NQB (SS / QB)      // 32
#define KVT 64
#define NKV (SS / KVT)     // 64
#define TILE_BYTES 8192    // 64 x 64 bf16

typedef float  fx4    __attribute__((ext_vector_type(4)));
typedef __bf16 bf16x8 __attribute__((ext_vector_type(8)));
typedef short  sx4    __attribute__((ext_vector_type(4)));

typedef __attribute__((address_space(1))) const unsigned int GU32;
typedef __attribute__((address_space(3))) unsigned int       LU32;

__device__ __forceinline__ void gload16(const void* g, void* l) {
    __builtin_amdgcn_global_load_lds((GU32*)g, (LU32*)l, 16, 0, 0);
}

__device__ __forceinline__ float fast_exp2(float x) {
    return __builtin_amdgcn_exp2f(x);   // v_exp_f32: 2^x
}

// ---------------- pre-pass: f32 K/V -> bf16 swizzled tile images ----------------
__global__ __launch_bounds__(256)
void prep_kernel(const float* __restrict__ Kg, const float* __restrict__ Vg,
                 char* __restrict__ Kimg, char* __restrict__ Vimg)
{
    __shared__ __bf16 lv[64][72];
    const int tid = threadIdx.x;
    const int h = (int)blockIdx.x >> 6;
    const int t = (int)blockIdx.x & 63;
    const int r = tid >> 2;                       // 0..63
    const size_t rowbase = ((size_t)h * SS + (size_t)t * KVT) * DD;

    // ---- K ----
    {
        char* kdst = Kimg + (size_t)(h * NKV + t) * TILE_BYTES;
        const float* src = Kg + rowbase + (size_t)r * DD;
#pragma unroll
        for (int cc = 0; cc < 2; ++cc) {
            const int c = (tid & 3) * 2 + cc;     // 0..7
            fx4 f0 = *(const fx4*)(src + c * 8);
            fx4 f1 = *(const fx4*)(src + c * 8 + 4);
            bf16x8 b;
#pragma unroll
            for (int j = 0; j < 4; ++j) { b[j] = (__bf16)f0[j]; b[4 + j] = (__bf16)f1[j]; }
            *(bf16x8*)(kdst + r * 128 + ((c ^ (r & 7)) << 4)) = b;
        }
    }

    // ---- V: load tile to LDS (row-major), then write transposed ----
    {
        const float* src = Vg + rowbase + (size_t)r * DD + (tid & 3) * 16;
#pragma unroll
        for (int qq = 0; qq < 4; ++qq) {
            fx4 f = *(const fx4*)(src + qq * 4);
#pragma unroll
            for (int j = 0; j < 4; ++j) lv[r][(tid & 3) * 16 + qq * 4 + j] = (__bf16)f[j];
        }
    }
    __syncthreads();
    {
        char* vdst = Vimg + (size_t)(h * NKV + t) * TILE_BYTES;
        const int d = r;                          // VT row
#pragma unroll
        for (int cc = 0; cc < 2; ++cc) {
            const int c = (tid & 3) * 2 + cc;     // k-chunk 0..7
            bf16x8 b;
#pragma unroll
            for (int j = 0; j < 8; ++j) b[j] = lv[c * 8 + j][d];
            *(bf16x8*)(vdst + d * 128 + ((c ^ (d & 7)) << 4)) = b;
        }
    }
}

// ---------------- main flash-attention kernel: 8 waves x 16 q-rows ----------------
__global__ __launch_bounds__(512, 4)
void attn_fwd(const float* __restrict__ Qg, const char* __restrict__ Kimg,
              const char* __restrict__ Vimg, float* __restrict__ Og)
{
    __shared__ __align__(16) char lK[2][TILE_BYTES];
    __shared__ __align__(16) char lV[2][TILE_BYTES];

    const int tid  = threadIdx.x;
    const int wid  = tid >> 6;                    // 0..7
    const int lane = tid & 63;
    const int lr   = lane & 15;
    const int g    = lane >> 4;

    // XCD-aware pairing: blocks b and b+256 co-locate on a CU under
    // round-robin XCD assignment; qb(b) + qb(b+256) = 31 -> constant work.
    const int b  = (int)blockIdx.x;
    const int h  = b & 15;
    const int sl = (b >> 4) & 15;                 // 0..15
    const int qb = (b >> 8) ? sl : (31 - sl);

    const int ntiles = 2 * qb + 2;
    const int q0     = qb * QB + wid * 16;        // wave owns 16 q rows

    const float* Qh = Qg + (size_t)h * SS * DD;
    float*       Oh = Og + (size_t)h * SS * DD;
    const char*  Kh = Kimg + (size_t)(h * NKV) * TILE_BYTES;
    const char*  Vh = Vimg + (size_t)(h * NKV) * TILE_BYTES;

    // fold 1/sqrt(64) and log2(e): softmax via exp2 (THR below in log2 units)
    const float QSCALE = 0.125f * 1.44269504088896f;

    // Q fragments (held all kernel)
    bf16x8 qa[2];
    {
        const int qrow = q0 + lr;
#pragma unroll
        for (int h2 = 0; h2 < 2; ++h2) {
            const float* src = Qh + (size_t)qrow * DD + h2 * 32 + g * 8;
            fx4 f0 = *(const fx4*)(src);
            fx4 f1 = *(const fx4*)(src + 4);
            bf16x8 tq;
#pragma unroll
            for (int j = 0; j < 4; ++j) {
                tq[j]     = (__bf16)(f0[j] * QSCALE);
                tq[j + 4] = (__bf16)(f1[j] * QSCALE);
            }
            qa[h2] = tq;
        }
    }

    fx4 acc[4];
#pragma unroll
    for (int d0 = 0; d0 < 4; ++d0) acc[d0] = (fx4){0.f, 0.f, 0.f, 0.f};
    float m_run = -1e30f;          // wave-level shared max (log2 units)
    float l_run = 0.f;             // lane-local partial row sum

    // staging: waves 0..3 -> K tile, waves 4..7 -> V tile; 2 x 1KB per wave
#define STAGE(buf, tt)                                                          \
    do {                                                                        \
        const int sw_ = wid & 3;                                                \
        const char* src_ = ((wid < 4) ? Kh : Vh) + (size_t)(tt) * TILE_BYTES    \
                           + sw_ * 2048 + lane * 16;                            \
        char* dst_ = ((wid < 4) ? &lK[buf][0] : &lV[buf][0]) + sw_ * 2048;      \
        gload16(src_,        dst_);                                             \
        gload16(src_ + 1024, dst_ + 1024);                                      \
    } while (0)

    STAGE(0, 0);
    __syncthreads();

    int cur = 0;
    for (int t = 0; t < ntiles; ++t) {
        if (t + 1 < ntiles) STAGE(cur ^ 1, t + 1);   // prefetch next tile

        // ---- QK^T (swapped: A=K tile rows, B=Q) ----
        float s[4][4];
        __builtin_amdgcn_s_setprio(1);
#pragma unroll
        for (int ks = 0; ks < 4; ++ks) {
            const int row = ks * 16 + lr;
            const char* base = &lK[cur][row * 128];
            const bf16x8 ka0 = *(const bf16x8*)(base + (((g    ) ^ (row & 7)) << 4));
            const bf16x8 ka1 = *(const bf16x8*)(base + (((g ^ 4) ^ (row & 7)) << 4));
            fx4 st = (fx4){0.f, 0.f, 0.f, 0.f};
            st = __builtin_amdgcn_mfma_f32_16x16x32_bf16(ka0, qa[0], st, 0, 0, 0);
            st = __builtin_amdgcn_mfma_f32_16x16x32_bf16(ka1, qa[1], st, 0, 0, 0);
#pragma unroll
            for (int r = 0; r < 4; ++r) s[ks][r] = st[r];
        }
        __builtin_amdgcn_s_setprio(0);

        // ---- causal mask: only the last two tiles can touch the diagonal ----
        if (t >= ntiles - 2) {
            const int kv0 = t * KVT;
            const int qrow = q0 + lr;
#pragma unroll
            for (int ks = 0; ks < 4; ++ks)
#pragma unroll
                for (int r = 0; r < 4; ++r) {
                    const int kk = kv0 + ks * 16 + 4 * g + r;
                    if (kk > qrow) s[ks][r] = -1e30f;
                }
        }

        // ---- wave-level online softmax, defer-max (THR=8 log2 -> P<=256) ----
        float tmax = fmaxf(
            fmaxf(fmaxf(fmaxf(s[0][0], s[0][1]), fmaxf(s[0][2], s[0][3])),
                  fmaxf(fmaxf(s[1][0], s[1][1]), fmaxf(s[1][2], s[1][3]))),
            fmaxf(fmaxf(fmaxf(s[2][0], s[2][1]), fmaxf(s[2][2], s[2][3])),
                  fmaxf(fmaxf(s[3][0], s[3][1]), fmaxf(s[3][2], s[3][3]))));
        tmax = fmaxf(tmax, __shfl_xor(tmax, 16));
        tmax = fmaxf(tmax, __shfl_xor(tmax, 32));   // wave-uniform now

        if (tmax > m_run + 8.0f) {                  // uniform branch; rare after t=0
            const float alpha = fast_exp2(m_run - tmax);
            m_run = tmax;
            l_run *= alpha;
#pragma unroll
            for (int d0 = 0; d0 < 4; ++d0) {
                fx4 a = acc[d0];
                a[0] *= alpha; a[1] *= alpha; a[2] *= alpha; a[3] *= alpha;
                acc[d0] = a;
            }
        }

        sx4 pa[4];
        {
            float e[4][4];
#pragma unroll
            for (int ks = 0; ks < 4; ++ks)
#pragma unroll
                for (int r = 0; r < 4; ++r)
                    e[ks][r] = fast_exp2(s[ks][r] - m_run);
            const float t0 = (e[0][0] + e[0][1]) + (e[0][2] + e[0][3]);
            const float t1 = (e[1][0] + e[1][1]) + (e[1][2] + e[1][3]);
            const float t2 = (e[2][0] + e[2][1]) + (e[2][2] + e[2][3]);
            const float t3 = (e[3][0] + e[3][1]) + (e[3][2] + e[3][3]);
            l_run += (t0 + t1) + (t2 + t3);
#pragma unroll
            for (int ks = 0; ks < 4; ++ks) {
                sx4 t4;
#pragma unroll
                for (int j = 0; j < 4; ++j) {
                    const __bf16 pb = (__bf16)e[ks][j];
                    t4[j] = __builtin_bit_cast(short, pb);
                }
                pa[ks] = t4;
            }
        }

        // ---- PV: P fragments are already MFMA A-layout; V^T read swizzled ----
        __builtin_amdgcn_s_setprio(1);
#pragma unroll
        for (int ks = 0; ks < 4; ++ks) {
            const int s0 = ks * 2 + (g >> 1);     // k-chunk slot
#pragma unroll
            for (int d0 = 0; d0 < 4; ++d0) {
                const int row = d0 * 16 + lr;
                const sx4 vb = *(const sx4*)(&lV[cur][row * 128 +
                                ((s0 ^ (row & 7)) << 4) + (g & 1) * 8]);
                acc[d0] = __builtin_amdgcn_mfma_f32_16x16x16bf16_1k(pa[ks], vb, acc[d0], 0, 0, 0);
            }
        }
        __builtin_amdgcn_s_setprio(0);

        if (t + 1 < ntiles) __syncthreads();      // next tile staged + all reads done
        cur ^= 1;
    }

    // ---- epilogue: one cross-lane l reduce, normalize, store ----
    {
        float ls = l_run;
        ls += __shfl_xor(ls, 16);
        ls += __shfl_xor(ls, 32);
        const float linv = 1.f / ls;
        float bv[4];
#pragma unroll
        for (int r = 0; r < 4; ++r) bv[r] = __shfl(linv, 4 * g + r);
#pragma unroll
        for (int d0 = 0; d0 < 4; ++d0)
#pragma unroll
            for (int r = 0; r < 4; ++r)
                Oh[(size_t)(q0 + 4 * g + r) * DD + d0 * 16 + lr] = acc[d0][r] * bv[r];
    }
}

extern "C" void kernel_launch(void* const* d_in, const int* in_sizes, int n_in,
                              void* d_out, int out_size, void* d_ws, size_t ws_size,
                              hipStream_t stream)
{
    (void)in_sizes; (void)n_in; (void)out_size; (void)ws_size;
    const float* q = (const float*)d_in[0];
    const float* k = (const float*)d_in[1];
    const float* v = (const float*)d_in[2];
    float*       o = (float*)d_out;

    char* ws   = (char*)d_ws;
    char* Kimg = ws;                       // 8 MB
    char* Vimg = ws + ((size_t)1 << 23);   // 8 MB

    hipLaunchKernelGGL(prep_kernel, dim3(NH * NKV), dim3(256), 0, stream, k, v, Kimg, Vimg);
    hipLaunchKernelGGL(attn_fwd,    dim3(NH * NQB), dim3(512), 0, stream, q, Kimg, Vimg, o);
}

// Round 6
// 82.844 us; speedup vs baseline: 1.5568x; 1.0994x over previous
//
#include <hip/hip_runtime.h>

#define SS 4096
#define DD 64
#define NH 16
#define QB 128
#define NQB (SS / QB)      // 32
#define KVT 64
#define NKV (SS / KVT)     // 64
#define TILE_BYTES 8192    // 64 x 64 bf16

typedef float  fx4    __attribute__((ext_vector_type(4)));
typedef __bf16 bf16x8 __attribute__((ext_vector_type(8)));
typedef short  sx4    __attribute__((ext_vector_type(4)));

typedef __attribute__((address_space(1))) const unsigned int GU32;
typedef __attribute__((address_space(3))) unsigned int       LU32;

__device__ __forceinline__ void gload16(const void* g, void* l) {
    __builtin_amdgcn_global_load_lds((GU32*)g, (LU32*)l, 16, 0, 0);
}

__device__ __forceinline__ float fast_exp2(float x) {
    return __builtin_amdgcn_exp2f(x);   // v_exp_f32: 2^x
}

// ---------------- pre-pass: f32 K/V -> bf16 swizzled tile images ----------------
__global__ __launch_bounds__(256)
void prep_kernel(const float* __restrict__ Kg, const float* __restrict__ Vg,
                 char* __restrict__ Kimg, char* __restrict__ Vimg)
{
    __shared__ __bf16 lv[64][72];
    const int tid = threadIdx.x;
    const int h = (int)blockIdx.x >> 6;
    const int t = (int)blockIdx.x & 63;
    const int r = tid >> 2;                       // 0..63
    const size_t rowbase = ((size_t)h * SS + (size_t)t * KVT) * DD;

    // ---- K ----
    {
        char* kdst = Kimg + (size_t)(h * NKV + t) * TILE_BYTES;
        const float* src = Kg + rowbase + (size_t)r * DD;
#pragma unroll
        for (int cc = 0; cc < 2; ++cc) {
            const int c = (tid & 3) * 2 + cc;     // 0..7
            fx4 f0 = *(const fx4*)(src + c * 8);
            fx4 f1 = *(const fx4*)(src + c * 8 + 4);
            bf16x8 b;
#pragma unroll
            for (int j = 0; j < 4; ++j) { b[j] = (__bf16)f0[j]; b[4 + j] = (__bf16)f1[j]; }
            *(bf16x8*)(kdst + r * 128 + ((c ^ (r & 7)) << 4)) = b;
        }
    }

    // ---- V: load tile to LDS (row-major), then write transposed ----
    {
        const float* src = Vg + rowbase + (size_t)r * DD + (tid & 3) * 16;
#pragma unroll
        for (int qq = 0; qq < 4; ++qq) {
            fx4 f = *(const fx4*)(src + qq * 4);
#pragma unroll
            for (int j = 0; j < 4; ++j) lv[r][(tid & 3) * 16 + qq * 4 + j] = (__bf16)f[j];
        }
    }
    __syncthreads();
    {
        char* vdst = Vimg + (size_t)(h * NKV + t) * TILE_BYTES;
        const int d = r;                          // VT row
#pragma unroll
        for (int cc = 0; cc < 2; ++cc) {
            const int c = (tid & 3) * 2 + cc;     // k-chunk 0..7
            bf16x8 b;
#pragma unroll
            for (int j = 0; j < 8; ++j) b[j] = lv[c * 8 + j][d];
            *(bf16x8*)(vdst + d * 128 + ((c ^ (d & 7)) << 4)) = b;
        }
    }
}

// ---------------- main flash-attention kernel: equal-work X/Y split ----------------
// s<16 (X): full light q-block p=s (final) + head [0,32-2p) of heavy H=31-s
//           (raw acc -> Og, l/m -> lmW planes 0/1)
// s>=16 (Y): tail [2H-30, 2H+2) of heavy H=47-s (acc -> accY, l/m -> planes 2/3)
__global__ __launch_bounds__(512, 4)
void attn_fwd(const float* __restrict__ Qg, const char* __restrict__ Kimg,
              const char* __restrict__ Vimg, float* __restrict__ Og,
              float* __restrict__ accY, float* __restrict__ lmW)
{
    __shared__ __align__(16) char lK[2][TILE_BYTES];
    __shared__ __align__(16) char lV[2][TILE_BYTES];

    const int tid  = threadIdx.x;
    const int wid  = tid >> 6;                    // 0..7
    const int lane = tid & 63;
    const int lr   = lane & 15;
    const int g    = lane >> 4;

    const int b = (int)blockIdx.x;
    const int h = b & 15;
    const int s = b >> 4;                         // 0..31
    const bool isX = (s < 16);

    int nph, ph_q[2], ph_t0[2], ph_t1[2], ph_mode[2];
    if (isX) {
        nph = 2;
        ph_q[0] = s;      ph_t0[0] = 0; ph_t1[0] = 2 * s + 2;  ph_mode[0] = 0;
        ph_q[1] = 31 - s; ph_t0[1] = 0; ph_t1[1] = 32 - 2 * s; ph_mode[1] = 1;
    } else {
        const int H = 47 - s;
        nph = 1;
        ph_q[0] = H; ph_t0[0] = 2 * H - 30; ph_t1[0] = 2 * H + 2; ph_mode[0] = 2;
    }

    const float* Qh = Qg + (size_t)h * SS * DD;
    float*       Oh = Og + (size_t)h * SS * DD;
    const char*  Kh = Kimg + (size_t)(h * NKV) * TILE_BYTES;
    const char*  Vh = Vimg + (size_t)(h * NKV) * TILE_BYTES;

    const float QSCALE = 0.125f * 1.44269504088896f;   // 1/sqrt(64) * log2(e)

#define STAGE(buf, tt)                                                          \
    do {                                                                        \
        const int sw_ = wid & 3;                                                \
        const char* src_ = ((wid < 4) ? Kh : Vh) + (size_t)(tt) * TILE_BYTES    \
                           + sw_ * 2048 + lane * 16;                            \
        char* dst_ = ((wid < 4) ? &lK[buf][0] : &lV[buf][0]) + sw_ * 2048;      \
        gload16(src_,        dst_);                                             \
        gload16(src_ + 1024, dst_ + 1024);                                      \
    } while (0)

    for (int ph = 0; ph < nph; ++ph) {
        const int qblk = ph_q[ph];
        const int t0   = ph_t0[ph];
        const int t1   = ph_t1[ph];
        const int mode = ph_mode[ph];
        const bool maskph = (mode != 1);          // mode 1 never reaches diagonal

        const int q0 = qblk * QB + wid * 16;      // wave owns 16 q rows

        // Q fragments for this phase
        bf16x8 qa[2];
        {
            const int qrow = q0 + lr;
#pragma unroll
            for (int h2 = 0; h2 < 2; ++h2) {
                const float* src = Qh + (size_t)qrow * DD + h2 * 32 + g * 8;
                fx4 f0 = *(const fx4*)(src);
                fx4 f1 = *(const fx4*)(src + 4);
                bf16x8 tq;
#pragma unroll
                for (int j = 0; j < 4; ++j) {
                    tq[j]     = (__bf16)(f0[j] * QSCALE);
                    tq[j + 4] = (__bf16)(f1[j] * QSCALE);
                }
                qa[h2] = tq;
            }
        }

        fx4 acc[4];
#pragma unroll
        for (int d0 = 0; d0 < 4; ++d0) acc[d0] = (fx4){0.f, 0.f, 0.f, 0.f};
        float m_run = -1e30f;       // wave-level shared max (log2 units)
        float l_run = 0.f;          // lane-local partial row sum

        __syncthreads();            // LDS safe to restage (prev phase readers done)
        STAGE(0, t0);
        __syncthreads();

        int cur = 0;
        for (int t = t0; t < t1; ++t) {
            if (t + 1 < t1) STAGE(cur ^ 1, t + 1);   // prefetch next tile

            // ---- QK^T (swapped: A=K tile rows, B=Q) ----
            float sc[4][4];
            __builtin_amdgcn_s_setprio(1);
#pragma unroll
            for (int ks = 0; ks < 4; ++ks) {
                const int row = ks * 16 + lr;
                const char* base = &lK[cur][row * 128];
                const bf16x8 ka0 = *(const bf16x8*)(base + (((g    ) ^ (row & 7)) << 4));
                const bf16x8 ka1 = *(const bf16x8*)(base + (((g ^ 4) ^ (row & 7)) << 4));
                fx4 st = (fx4){0.f, 0.f, 0.f, 0.f};
                st = __builtin_amdgcn_mfma_f32_16x16x32_bf16(ka0, qa[0], st, 0, 0, 0);
                st = __builtin_amdgcn_mfma_f32_16x16x32_bf16(ka1, qa[1], st, 0, 0, 0);
#pragma unroll
                for (int r = 0; r < 4; ++r) sc[ks][r] = st[r];
            }
            __builtin_amdgcn_s_setprio(0);

            // ---- causal mask: last two tiles of a diagonal-reaching phase ----
            if (maskph && t >= t1 - 2) {
                const int kv0 = t * KVT;
                const int qrow = q0 + lr;
#pragma unroll
                for (int ks = 0; ks < 4; ++ks)
#pragma unroll
                    for (int r = 0; r < 4; ++r) {
                        const int kk = kv0 + ks * 16 + 4 * g + r;
                        if (kk > qrow) sc[ks][r] = -1e30f;
                    }
            }

            // ---- wave-level online softmax, defer-max (THR=8 log2) ----
            float tmax = fmaxf(
                fmaxf(fmaxf(fmaxf(sc[0][0], sc[0][1]), fmaxf(sc[0][2], sc[0][3])),
                      fmaxf(fmaxf(sc[1][0], sc[1][1]), fmaxf(sc[1][2], sc[1][3]))),
                fmaxf(fmaxf(fmaxf(sc[2][0], sc[2][1]), fmaxf(sc[2][2], sc[2][3])),
                      fmaxf(fmaxf(sc[3][0], sc[3][1]), fmaxf(sc[3][2], sc[3][3]))));
            tmax = fmaxf(tmax, __shfl_xor(tmax, 16));
            tmax = fmaxf(tmax, __shfl_xor(tmax, 32));   // wave-uniform

            if (tmax > m_run + 8.0f) {                  // uniform branch, rare
                const float alpha = fast_exp2(m_run - tmax);
                m_run = tmax;
                l_run *= alpha;
#pragma unroll
                for (int d0 = 0; d0 < 4; ++d0) {
                    fx4 a = acc[d0];
                    a[0] *= alpha; a[1] *= alpha; a[2] *= alpha; a[3] *= alpha;
                    acc[d0] = a;
                }
            }

            sx4 pa[4];
            {
                float e[4][4];
#pragma unroll
                for (int ks = 0; ks < 4; ++ks)
#pragma unroll
                    for (int r = 0; r < 4; ++r)
                        e[ks][r] = fast_exp2(sc[ks][r] - m_run);
                const float u0 = (e[0][0] + e[0][1]) + (e[0][2] + e[0][3]);
                const float u1 = (e[1][0] + e[1][1]) + (e[1][2] + e[1][3]);
                const float u2 = (e[2][0] + e[2][1]) + (e[2][2] + e[2][3]);
                const float u3 = (e[3][0] + e[3][1]) + (e[3][2] + e[3][3]);
                l_run += (u0 + u1) + (u2 + u3);
#pragma unroll
                for (int ks = 0; ks < 4; ++ks) {
                    sx4 t4;
#pragma unroll
                    for (int j = 0; j < 4; ++j) {
                        const __bf16 pb = (__bf16)e[ks][j];
                        t4[j] = __builtin_bit_cast(short, pb);
                    }
                    pa[ks] = t4;
                }
            }

            // ---- PV ----
            __builtin_amdgcn_s_setprio(1);
#pragma unroll
            for (int ks = 0; ks < 4; ++ks) {
                const int s0 = ks * 2 + (g >> 1);
#pragma unroll
                for (int d0 = 0; d0 < 4; ++d0) {
                    const int row = d0 * 16 + lr;
                    const sx4 vb = *(const sx4*)(&lV[cur][row * 128 +
                                    ((s0 ^ (row & 7)) << 4) + (g & 1) * 8]);
                    acc[d0] = __builtin_amdgcn_mfma_f32_16x16x16bf16_1k(pa[ks], vb, acc[d0], 0, 0, 0);
                }
            }
            __builtin_amdgcn_s_setprio(0);

            if (t + 1 < t1) __syncthreads();
            cur ^= 1;
        }

        // ---- phase epilogue ----
        float ls = l_run;
        ls += __shfl_xor(ls, 16);
        ls += __shfl_xor(ls, 32);           // all lanes: row-sum for row q0+lr

        if (mode == 0) {                    // final: normalize and store
            const float linv = 1.f / ls;
            float bv[4];
#pragma unroll
            for (int r = 0; r < 4; ++r) bv[r] = __shfl(linv, 4 * g + r);
#pragma unroll
            for (int d0 = 0; d0 < 4; ++d0)
#pragma unroll
                for (int r = 0; r < 4; ++r)
                    Oh[(size_t)(q0 + 4 * g + r) * DD + d0 * 16 + lr] = acc[d0][r] * bv[r];
        } else {
            const int hb = qblk - 16;                       // 0..15
            const int lmbase = (h * 16 + hb) * 128;
            if (mode == 1) {                // X partial: raw acc -> Og, l/m plane 0/1
#pragma unroll
                for (int d0 = 0; d0 < 4; ++d0)
#pragma unroll
                    for (int r = 0; r < 4; ++r)
                        Oh[(size_t)(q0 + 4 * g + r) * DD + d0 * 16 + lr] = acc[d0][r];
                if (lane < 16) {
                    lmW[lmbase + wid * 16 + lr]         = m_run;
                    lmW[32768 + lmbase + wid * 16 + lr] = ls;
                }
            } else {                        // Y partial: acc -> accY, l/m plane 2/3
                float* ab = accY + (size_t)(lmbase + wid * 16) * 64;
#pragma unroll
                for (int d0 = 0; d0 < 4; ++d0)
#pragma unroll
                    for (int r = 0; r < 4; ++r)
                        ab[(size_t)(4 * g + r) * 64 + d0 * 16 + lr] = acc[d0][r];
                if (lane < 16) {
                    lmW[65536 + lmbase + wid * 16 + lr] = m_run;
                    lmW[98304 + lmbase + wid * 16 + lr] = ls;
                }
            }
        }
    }
#undef STAGE
}

// ---------------- combine partials for heavy q-blocks ----------------
__global__ __launch_bounds__(256)
void combine_kernel(float* __restrict__ Og, const float* __restrict__ accY,
                    const float* __restrict__ lmW)
{
    const int blk = (int)blockIdx.x;      // 0..255
    const int h = blk >> 4, hb = blk & 15;
    const int t = threadIdx.x;
    const int col = t & 63;
    const int r0  = t >> 6;               // 0..3
    const int lmbase = (h * 16 + hb) * 128;
    const size_t obase = ((size_t)h * SS + (size_t)(16 + hb) * 128) * DD;

    for (int rr = 0; rr < 32; ++rr) {
        const int row = rr * 4 + r0;
        const float mx = lmW[lmbase + row];
        const float lx = lmW[32768 + lmbase + row];
        const float my = lmW[65536 + lmbase + row];
        const float ly = lmW[98304 + lmbase + row];
        const float mm = fmaxf(mx, my);
        const float a  = fast_exp2(mx - mm);
        const float bb = fast_exp2(my - mm);
        const float den = a * lx + bb * ly;
        const size_t oi = obase + (size_t)row * DD + col;
        const float v = a * Og[oi] + bb * accY[(size_t)(lmbase + row) * 64 + col];
        Og[oi] = v / den;
    }
}

extern "C" void kernel_launch(void* const* d_in, const int* in_sizes, int n_in,
                              void* d_out, int out_size, void* d_ws, size_t ws_size,
                              hipStream_t stream)
{
    (void)in_sizes; (void)n_in; (void)out_size; (void)ws_size;
    const float* q = (const float*)d_in[0];
    const float* k = (const float*)d_in[1];
    const float* v = (const float*)d_in[2];
    float*       o = (float*)d_out;

    char* ws    = (char*)d_ws;
    char* Kimg  = ws;                                  // 8 MB
    char* Vimg  = ws + ((size_t)1 << 23);              // 8 MB
    float* accY = (float*)(ws + ((size_t)2 << 23));    // 8 MB
    float* lmW  = (float*)(ws + ((size_t)3 << 23));    // 512 KB (4 planes x 32768 f32)

    hipLaunchKernelGGL(prep_kernel,    dim3(NH * NKV), dim3(256), 0, stream, k, v, Kimg, Vimg);
    hipLaunchKernelGGL(attn_fwd,       dim3(512),      dim3(512), 0, stream, q, Kimg, Vimg, o, accY, lmW);
    hipLaunchKernelGGL(combine_kernel, dim3(256),      dim3(256), 0, stream, o, accY, lmW);
}